// Round 1
// baseline (216.094 us; speedup 1.0000x reference)
//
#include <hip/hip_runtime.h>

// Shapes (fixed by setup_inputs): x [T=4, B=16, C=512, N=1024] fp32
// out [T,B,C,1] = [64, 512] fp32
#define T_  4
#define B_  16
#define C_  512
#define N_  1024
#define CR_ 64

static constexpr float BN_EPS = 1e-5f;

// ---------------------------------------------------------------------------
// K1: LIF 4-step recurrence + global-average-pool over N.
// One block per (b, c): 256 threads x float4 = 1024 = N elements.
// v <- (v + x_t) * 0.5 ; s = (v >= 1) ; v *= (1 - s)   [hard reset to 0]
// g[(t*B + b)*C + c] = mean_n s
// ---------------------------------------------------------------------------
__global__ __launch_bounds__(256) void lif_gap_kernel(
    const float* __restrict__ x, float* __restrict__ g) {
    const int blk = blockIdx.x;          // b*C + c ; consecutive blocks -> consecutive c (coalesced planes)
    const int b   = blk >> 9;            // / 512
    const int c   = blk & (C_ - 1);
    const int tid = threadIdx.x;
    const size_t plane = (size_t)B_ * C_ * N_;
    const size_t base  = ((size_t)(b * C_ + c)) * N_ + (size_t)tid * 4;

    float4 v = make_float4(0.f, 0.f, 0.f, 0.f);
    float sum[T_];
#pragma unroll
    for (int t = 0; t < T_; ++t) {
        const float4 xv = *(const float4*)(x + base + (size_t)t * plane);
        v.x = 0.5f * (v.x + xv.x);
        v.y = 0.5f * (v.y + xv.y);
        v.z = 0.5f * (v.z + xv.z);
        v.w = 0.5f * (v.w + xv.w);
        const float s0 = (v.x >= 1.0f) ? 1.f : 0.f;
        const float s1 = (v.y >= 1.0f) ? 1.f : 0.f;
        const float s2 = (v.z >= 1.0f) ? 1.f : 0.f;
        const float s3 = (v.w >= 1.0f) ? 1.f : 0.f;
        sum[t] = s0 + s1 + s2 + s3;
        v.x *= (1.f - s0);
        v.y *= (1.f - s1);
        v.z *= (1.f - s2);
        v.w *= (1.f - s3);
    }

    // wave(64)-level butterfly reduction of the 4 per-t sums
#pragma unroll
    for (int t = 0; t < T_; ++t) {
#pragma unroll
        for (int off = 32; off >= 1; off >>= 1)
            sum[t] += __shfl_xor(sum[t], off, 64);
    }

    __shared__ float lds[4 * T_];        // 4 waves x 4 t-values
    const int wave = tid >> 6;
    const int lane = tid & 63;
    if (lane == 0) {
#pragma unroll
        for (int t = 0; t < T_; ++t) lds[wave * T_ + t] = sum[t];
    }
    __syncthreads();
    if (tid < T_) {                      // thread tid finalizes timestep t = tid
        const float tot = lds[0 * T_ + tid] + lds[1 * T_ + tid] +
                          lds[2 * T_ + tid] + lds[3 * T_ + tid];
        g[((size_t)(tid * B_ + b)) * C_ + c] = tot * (1.0f / N_);
    }
}

// ---------------------------------------------------------------------------
// K2: h1 = BN1(g @ w1^T + b1), h1 is [64 rows (TB), 64 cols (Cr)].
// One block per output column j (Cr). 4 waves; wave w computes rows w,w+4,...
// via length-512 dot with wave butterfly reduce. Then wave 0 does the
// batch-dim (64-row) mean/var and writes BN'd column.
// ---------------------------------------------------------------------------
__global__ __launch_bounds__(256) void fc1_bn_kernel(
    const float* __restrict__ g,  const float* __restrict__ w1,
    const float* __restrict__ b1, const float* __restrict__ gamma1,
    const float* __restrict__ beta1, float* __restrict__ h1) {
    const int j    = blockIdx.x;         // 0..63
    const int tid  = threadIdx.x;
    const int lane = tid & 63;
    const int wave = tid >> 6;
    __shared__ float rowval[64];

    const float* __restrict__ w1r = w1 + (size_t)j * C_;
    for (int i = wave; i < 64; i += 4) {
        float p = 0.f;
        const float* __restrict__ gr = g + (size_t)i * C_;
#pragma unroll
        for (int m = 0; m < C_ / 64; ++m) {
            const int k = lane + 64 * m;
            p += gr[k] * w1r[k];
        }
#pragma unroll
        for (int off = 32; off >= 1; off >>= 1) p += __shfl_xor(p, off, 64);
        if (lane == 0) rowval[i] = p + b1[j];
    }
    __syncthreads();
    if (tid < 64) {                      // exactly wave 0 (wavefront = 64)
        const float v = rowval[tid];
        float s  = v;
        float s2 = v * v;
#pragma unroll
        for (int off = 32; off >= 1; off >>= 1) {
            s  += __shfl_xor(s,  off, 64);
            s2 += __shfl_xor(s2, off, 64);
        }
        const float mu  = s * (1.f / 64.f);
        const float var = s2 * (1.f / 64.f) - mu * mu;
        h1[(size_t)tid * CR_ + j] =
            (v - mu) * rsqrtf(var + BN_EPS) * gamma1[j] + beta1[j];
    }
}

// ---------------------------------------------------------------------------
// K3: out = BN2(h1 @ w2^T + b2), out is [64 rows (TB), 512 cols (C)].
// One block (= one wave) per output column j; lane = row. Dot of length 64,
// then butterfly mean/var across the 64 rows held one-per-lane.
// ---------------------------------------------------------------------------
__global__ __launch_bounds__(64) void fc2_bn_kernel(
    const float* __restrict__ h1, const float* __restrict__ w2,
    const float* __restrict__ b2, const float* __restrict__ gamma2,
    const float* __restrict__ beta2, float* __restrict__ out) {
    const int j = blockIdx.x;            // 0..511
    const int i = threadIdx.x;           // row 0..63
    const float* __restrict__ w2r = w2 + (size_t)j * CR_;
    const float* __restrict__ hr  = h1 + (size_t)i * CR_;
    float v = b2[j];
#pragma unroll
    for (int k = 0; k < CR_; ++k) v += hr[k] * w2r[k];

    float s  = v;
    float s2 = v * v;
#pragma unroll
    for (int off = 32; off >= 1; off >>= 1) {
        s  += __shfl_xor(s,  off, 64);
        s2 += __shfl_xor(s2, off, 64);
    }
    const float mu  = s * (1.f / 64.f);
    const float var = s2 * (1.f / 64.f) - mu * mu;
    out[(size_t)i * C_ + j] =
        (v - mu) * rsqrtf(var + BN_EPS) * gamma2[j] + beta2[j];
}

extern "C" void kernel_launch(void* const* d_in, const int* in_sizes, int n_in,
                              void* d_out, int out_size, void* d_ws, size_t ws_size,
                              hipStream_t stream) {
    const float* x      = (const float*)d_in[0];
    const float* w1     = (const float*)d_in[1];
    const float* b1     = (const float*)d_in[2];
    const float* gamma1 = (const float*)d_in[3];
    const float* beta1  = (const float*)d_in[4];
    const float* w2     = (const float*)d_in[5];
    const float* b2     = (const float*)d_in[6];
    const float* gamma2 = (const float*)d_in[7];
    const float* beta2  = (const float*)d_in[8];
    float* out = (float*)d_out;

    float* g  = (float*)d_ws;            // [64, 512]  = 128 KiB
    float* h1 = g + 64 * C_;             // [64, 64]   =  16 KiB

    lif_gap_kernel<<<B_ * C_, 256, 0, stream>>>(x, g);
    fc1_bn_kernel<<<CR_, 256, 0, stream>>>(g, w1, b1, gamma1, beta1, h1);
    fc2_bn_kernel<<<C_, 64, 0, stream>>>(h1, w2, b2, gamma2, beta2, out);
}

// Round 3
// 205.501 us; speedup vs baseline: 1.0515x; 1.0515x over previous
//
#include <hip/hip_runtime.h>

// Shapes (fixed by setup_inputs): x [T=4, B=16, C=512, N=1024] fp32
// out [T,B,C,1] = [64, 512] fp32
#define T_  4
#define B_  16
#define C_  512
#define N_  1024
#define CR_ 64

static constexpr float BN_EPS = 1e-5f;

typedef float f4_t __attribute__((ext_vector_type(4)));  // native vec for nontemporal builtin

// ---------------------------------------------------------------------------
// K1: LIF 4-step recurrence + global-average-pool over N.
// One block per (b, c): 256 threads x float4 = 1024 = N elements.
// v <- (v + x_t) * 0.5 ; s = (v >= 1) ; v = s ? 0 : v   [hard reset]
// Spike counting via ballot+popcount (scalar pipe) instead of shfl butterfly
// (LDS pipe) — spikes are {0,1} so popcount over the 64-bit ballot mask is
// the exact lane-sum.
// g[(t*B + b)*C + c] = count / N
// ---------------------------------------------------------------------------
__global__ __launch_bounds__(256) void lif_gap_kernel(
    const float* __restrict__ x, float* __restrict__ g) {
    const int blk = blockIdx.x;          // b*C + c ; consecutive blocks read consecutive 4KB chunks
    const int b   = blk >> 9;            // / 512
    const int c   = blk & (C_ - 1);
    const int tid = threadIdx.x;
    const size_t plane = (size_t)B_ * C_ * N_;
    const float* __restrict__ xp = x + ((size_t)(b * C_ + c)) * N_ + (size_t)tid * 4;

    f4_t v = (f4_t)(0.f);
    int cnt[T_];
#pragma unroll
    for (int t = 0; t < T_; ++t) {
        const f4_t* p = (const f4_t*)(xp + (size_t)t * plane);
        const f4_t xv = __builtin_nontemporal_load(p);
        v.x = 0.5f * (v.x + xv.x);
        v.y = 0.5f * (v.y + xv.y);
        v.z = 0.5f * (v.z + xv.z);
        v.w = 0.5f * (v.w + xv.w);
        // lane-sum of spikes across the wave via ballot+popcount (no LDS pipe)
        const unsigned long long m0 = __ballot(v.x >= 1.0f);
        const unsigned long long m1 = __ballot(v.y >= 1.0f);
        const unsigned long long m2 = __ballot(v.z >= 1.0f);
        const unsigned long long m3 = __ballot(v.w >= 1.0f);
        cnt[t] = (int)(__popcll(m0) + __popcll(m1) + __popcll(m2) + __popcll(m3));
        // hard reset
        v.x = (v.x >= 1.0f) ? 0.f : v.x;
        v.y = (v.y >= 1.0f) ? 0.f : v.y;
        v.z = (v.z >= 1.0f) ? 0.f : v.z;
        v.w = (v.w >= 1.0f) ? 0.f : v.w;
    }

    __shared__ int lds[4 * T_];          // 4 waves x 4 t-counts
    const int wave = tid >> 6;
    const int lane = tid & 63;
    if (lane == 0) {
#pragma unroll
        for (int t = 0; t < T_; ++t) lds[wave * T_ + t] = cnt[t];
    }
    __syncthreads();
    if (tid < T_) {                      // thread tid finalizes timestep t = tid
        const int tot = lds[0 * T_ + tid] + lds[1 * T_ + tid] +
                        lds[2 * T_ + tid] + lds[3 * T_ + tid];
        g[((size_t)(tid * B_ + b)) * C_ + c] = (float)tot * (1.0f / N_);
    }
}

// ---------------------------------------------------------------------------
// K2: h1 = BN1(g @ w1^T + b1), h1 is [64 rows (TB), 64 cols (Cr)].
// One block per output column j (Cr). 4 waves; wave w computes rows w,w+4,...
// via length-512 dot with wave butterfly reduce. Then wave 0 does the
// batch-dim (64-row) mean/var and writes BN'd column.
// ---------------------------------------------------------------------------
__global__ __launch_bounds__(256) void fc1_bn_kernel(
    const float* __restrict__ g,  const float* __restrict__ w1,
    const float* __restrict__ b1, const float* __restrict__ gamma1,
    const float* __restrict__ beta1, float* __restrict__ h1) {
    const int j    = blockIdx.x;         // 0..63
    const int tid  = threadIdx.x;
    const int lane = tid & 63;
    const int wave = tid >> 6;
    __shared__ float rowval[64];

    const float* __restrict__ w1r = w1 + (size_t)j * C_;
    for (int i = wave; i < 64; i += 4) {
        float p = 0.f;
        const float* __restrict__ gr = g + (size_t)i * C_;
#pragma unroll
        for (int m = 0; m < C_ / 64; ++m) {
            const int k = lane + 64 * m;
            p += gr[k] * w1r[k];
        }
#pragma unroll
        for (int off = 32; off >= 1; off >>= 1) p += __shfl_xor(p, off, 64);
        if (lane == 0) rowval[i] = p + b1[j];
    }
    __syncthreads();
    if (tid < 64) {                      // exactly wave 0 (wavefront = 64)
        const float v = rowval[tid];
        float s  = v;
        float s2 = v * v;
#pragma unroll
        for (int off = 32; off >= 1; off >>= 1) {
            s  += __shfl_xor(s,  off, 64);
            s2 += __shfl_xor(s2, off, 64);
        }
        const float mu  = s * (1.f / 64.f);
        const float var = s2 * (1.f / 64.f) - mu * mu;
        h1[(size_t)tid * CR_ + j] =
            (v - mu) * rsqrtf(var + BN_EPS) * gamma1[j] + beta1[j];
    }
}

// ---------------------------------------------------------------------------
// K3: out = BN2(h1 @ w2^T + b2), out is [64 rows (TB), 512 cols (C)].
// One block (= one wave) per output column j; lane = row. Dot of length 64,
// then butterfly mean/var across the 64 rows held one-per-lane.
// ---------------------------------------------------------------------------
__global__ __launch_bounds__(64) void fc2_bn_kernel(
    const float* __restrict__ h1, const float* __restrict__ w2,
    const float* __restrict__ b2, const float* __restrict__ gamma2,
    const float* __restrict__ beta2, float* __restrict__ out) {
    const int j = blockIdx.x;            // 0..511
    const int i = threadIdx.x;           // row 0..63
    const float* __restrict__ w2r = w2 + (size_t)j * CR_;
    const float* __restrict__ hr  = h1 + (size_t)i * CR_;
    float v = b2[j];
#pragma unroll
    for (int k = 0; k < CR_; ++k) v += hr[k] * w2r[k];

    float s  = v;
    float s2 = v * v;
#pragma unroll
    for (int off = 32; off >= 1; off >>= 1) {
        s  += __shfl_xor(s,  off, 64);
        s2 += __shfl_xor(s2, off, 64);
    }
    const float mu  = s * (1.f / 64.f);
    const float var = s2 * (1.f / 64.f) - mu * mu;
    out[(size_t)i * C_ + j] =
        (v - mu) * rsqrtf(var + BN_EPS) * gamma2[j] + beta2[j];
}

extern "C" void kernel_launch(void* const* d_in, const int* in_sizes, int n_in,
                              void* d_out, int out_size, void* d_ws, size_t ws_size,
                              hipStream_t stream) {
    const float* x      = (const float*)d_in[0];
    const float* w1     = (const float*)d_in[1];
    const float* b1     = (const float*)d_in[2];
    const float* gamma1 = (const float*)d_in[3];
    const float* beta1  = (const float*)d_in[4];
    const float* w2     = (const float*)d_in[5];
    const float* b2     = (const float*)d_in[6];
    const float* gamma2 = (const float*)d_in[7];
    const float* beta2  = (const float*)d_in[8];
    float* out = (float*)d_out;

    float* g  = (float*)d_ws;            // [64, 512]  = 128 KiB
    float* h1 = g + 64 * C_;             // [64, 64]   =  16 KiB

    lif_gap_kernel<<<B_ * C_, 256, 0, stream>>>(x, g);
    fc1_bn_kernel<<<CR_, 256, 0, stream>>>(g, w1, b1, gamma1, beta1, h1);
    fc2_bn_kernel<<<C_, 64, 0, stream>>>(h1, w2, b2, gamma2, beta2, out);
}